// Round 1
// baseline (4798.589 us; speedup 1.0000x reference)
//
#include <hip/hip_runtime.h>
#include <hip/hip_bf16.h>
#include <cstddef>

// ---------------------------------------------------------------------------
// StandardPartitionAttention — round 0: correctness-first fp32 implementation.
// B=4, C=D=256, H=W=128, WS=8 -> nW=1024 windows, n=64 tokens, 65536 rows.
// HEADS=8, DH=32, INNER=256, MLP=1024, DEPTH=2.
// ---------------------------------------------------------------------------

#define ROWS      65536      // nW * n
#define DMODEL    256
#define NWIN      1024
#define NTOK      64
#define NHEADS    8
#define DHEAD     32
#define QKV_N     768
#define MLP_N     1024
#define SCALE_F   0.17677669529663687f   // 32^-0.5
#define LN_EPS_F  1e-5f

// ---------------- window gather: x[B,C,H,W] -> Xg[row, c] -------------------
__global__ __launch_bounds__(256) void gather_k(const float* __restrict__ x,
                                                float* __restrict__ Xg) {
  size_t idx = (size_t)blockIdx.x * 256 + threadIdx.x;  // row*256 + c
  int c   = (int)(idx & 255);
  int row = (int)(idx >> 8);
  int i   = row & 63;          // token within window
  int wxy = row >> 6;
  int wx  = wxy & 15;
  int wy  = (wxy >> 4) & 15;
  int b   = wxy >> 8;
  int y   = wy * 8 + (i >> 3);
  int xx  = wx * 8 + (i & 7);
  Xg[idx] = x[(((size_t)b * 256 + c) * 128 + y) * 128 + xx];
}

// ---------------- un-window: t[row, d] -> out[B,D,H,W] ----------------------
__global__ __launch_bounds__(256) void unwindow_k(const float* __restrict__ t,
                                                  float* __restrict__ out) {
  size_t idx = (size_t)blockIdx.x * 256 + threadIdx.x;  // ((b*256+d)*128+y)*128+x
  int xx = (int)(idx & 127);
  size_t r = idx >> 7;
  int y = (int)(r & 127); r >>= 7;
  int d = (int)(r & 255);
  int b = (int)(r >> 8);
  int row = ((b * 16 + (y >> 3)) * 16 + (xx >> 3)) * 64 + (y & 7) * 8 + (xx & 7);
  out[idx] = t[(size_t)row * DMODEL + d];
}

// ---------------- LayerNorm: block per row, D=256 ---------------------------
__global__ __launch_bounds__(256) void ln_k(const float* __restrict__ X,
                                            float* __restrict__ Y,
                                            const float* __restrict__ g,
                                            const float* __restrict__ b) {
  const int row = blockIdx.x;
  const int tid = threadIdx.x;
  float x = X[(size_t)row * DMODEL + tid];
  float s = x, s2 = x * x;
#pragma unroll
  for (int off = 32; off > 0; off >>= 1) {
    s  += __shfl_down(s,  off);
    s2 += __shfl_down(s2, off);
  }
  __shared__ float ls[4], ls2[4];
  int wave = tid >> 6, lane = tid & 63;
  if (lane == 0) { ls[wave] = s; ls2[wave] = s2; }
  __syncthreads();
  if (tid == 0) {
    float ts  = ls[0] + ls[1] + ls[2] + ls[3];
    float ts2 = ls2[0] + ls2[1] + ls2[2] + ls2[3];
    float m   = ts * (1.0f / DMODEL);
    float var = ts2 * (1.0f / DMODEL) - m * m;
    ls[0]  = m;
    ls2[0] = rsqrtf(var + LN_EPS_F);
  }
  __syncthreads();
  float m = ls[0], rr = ls2[0];
  Y[(size_t)row * DMODEL + tid] = (x - m) * rr * g[tid] + b[tid];
}

// ---------------- fp32 tiled GEMM: C = A[M,K] @ B[K,N] (+bias)(+relu)(+res) -
// BM=BN=64, BK=16, 256 threads, 4x4 micro-tile per thread.
template <bool BIAS, bool RELU, bool RES>
__global__ __launch_bounds__(256) void gemm_k(const float* __restrict__ A,
                                              const float* __restrict__ B,
                                              const float* __restrict__ bias,
                                              const float* res, float* C,
                                              int M, int N, int K) {
  __shared__ float As[16][65];   // [k][m], padded
  __shared__ float Bs[16][64];   // [k][n]
  const int tid = threadIdx.x;
  const int bm = blockIdx.y << 6;
  const int bn = blockIdx.x << 6;
  const int tx = tid & 15, ty = tid >> 4;
  const int arow = tid >> 2, acol = (tid & 3) << 2;
  const int brow = tid >> 4, bcol = (tid & 15) << 2;
  float acc[4][4] = {};
  for (int k0 = 0; k0 < K; k0 += 16) {
    float4 a4 = *(const float4*)(A + (size_t)(bm + arow) * K + k0 + acol);
    As[acol + 0][arow] = a4.x;
    As[acol + 1][arow] = a4.y;
    As[acol + 2][arow] = a4.z;
    As[acol + 3][arow] = a4.w;
    *(float4*)(&Bs[brow][bcol]) =
        *(const float4*)(B + (size_t)(k0 + brow) * N + bn + bcol);
    __syncthreads();
#pragma unroll
    for (int k = 0; k < 16; ++k) {
      float ra[4], rb[4];
#pragma unroll
      for (int i = 0; i < 4; ++i) ra[i] = As[k][ty * 4 + i];
#pragma unroll
      for (int j = 0; j < 4; ++j) rb[j] = Bs[k][tx * 4 + j];
#pragma unroll
      for (int i = 0; i < 4; ++i)
#pragma unroll
        for (int j = 0; j < 4; ++j) acc[i][j] += ra[i] * rb[j];
    }
    __syncthreads();
  }
#pragma unroll
  for (int i = 0; i < 4; ++i) {
    int row = bm + ty * 4 + i;
    int col = bn + tx * 4;
    float4 v = make_float4(acc[i][0], acc[i][1], acc[i][2], acc[i][3]);
    if (BIAS) {
      v.x += bias[col + 0]; v.y += bias[col + 1];
      v.z += bias[col + 2]; v.w += bias[col + 3];
    }
    if (RELU) {
      v.x = fmaxf(v.x, 0.f); v.y = fmaxf(v.y, 0.f);
      v.z = fmaxf(v.z, 0.f); v.w = fmaxf(v.w, 0.f);
    }
    if (RES) {
      const float4 r4 = *(const float4*)(res + (size_t)row * N + col);
      v.x += r4.x; v.y += r4.y; v.z += r4.z; v.w += r4.w;
    }
    *(float4*)(C + (size_t)row * N + col) = v;
  }
}

// ---------------- attention: one block per (window, head) -------------------
__global__ __launch_bounds__(256) void attn_k(const float* __restrict__ qkv,
                                              float* __restrict__ o,
                                              float* __restrict__ attns_out,
                                              const float* __restrict__ bias_tbl,
                                              const float* __restrict__ sita_l) {
  const int w = blockIdx.x;
  const int head = blockIdx.y;
  const int tid = threadIdx.x;
  __shared__ float qs[64][33], ks[64][33], vs[64][33];
  __shared__ float s0[64][65], s1[64][65];

  // load q,k,v fragments for this head: 64x32 each
#pragma unroll
  for (int t = 0; t < 8; ++t) {
    int idx = tid + t * 256;          // 0..2047
    int i = idx >> 5, d = idx & 31;
    size_t rb = (size_t)(w * 64 + i) * QKV_N;
    int col = head * 32 + d;
    qs[i][d] = qkv[rb + col];
    ks[i][d] = qkv[rb + 256 + col];
    vs[i][d] = qkv[rb + 512 + col];
  }
  __syncthreads();

  float sita = sita_l[head];
  float factor = 1.0f / (2.0f * sita * sita + 1e-10f);

  // scores: dots0 (scaled) and dots (+bias +0.01*pos)
#pragma unroll
  for (int t = 0; t < 16; ++t) {
    int idx = tid + t * 256;
    int i = idx >> 6, j = idx & 63;
    float dot = 0.f;
#pragma unroll
    for (int d = 0; d < 32; ++d) dot += qs[i][d] * ks[j][d];
    float d0 = dot * SCALE_F;
    int iy = i >> 3, ix = i & 7, jy = j >> 3, jx = j & 7;
    int rpi = (iy - jy + 7) * 15 + (ix - jx + 7);
    float bias = bias_tbl[rpi * NHEADS + head];
    float dy = (float)(iy - jy) * 0.125f;
    float dx = (float)(ix - jx) * 0.125f;
    float pos = __expf(-factor * (dy * dy + dx * dx));
    s0[i][j] = d0;
    s1[i][j] = d0 + bias + 0.01f * pos;
  }
  __syncthreads();

  // row softmax, both matrices (s0: no bias -> attns output; s1: biased)
  if (tid < 64) {
    int i = tid;
    float m0 = -1e30f, m1 = -1e30f;
    for (int j = 0; j < 64; ++j) {
      m0 = fmaxf(m0, s0[i][j]);
      m1 = fmaxf(m1, s1[i][j]);
    }
    float z0 = 0.f, z1 = 0.f;
    for (int j = 0; j < 64; ++j) {
      float e0 = __expf(s0[i][j] - m0);
      float e1 = __expf(s1[i][j] - m1);
      s0[i][j] = e0; s1[i][j] = e1;
      z0 += e0; z1 += e1;
    }
    float r0 = 1.f / z0, r1 = 1.f / z1;
    for (int j = 0; j < 64; ++j) { s0[i][j] *= r0; s1[i][j] *= r1; }
  }
  __syncthreads();

  // write attn0 slice: attns_out[w][head][i][j]
  size_t abase = ((size_t)w * NHEADS + head) * 4096;
#pragma unroll
  for (int t = 0; t < 16; ++t) {
    int idx = tid + t * 256;
    attns_out[abase + idx] = s0[idx >> 6][idx & 63];
  }

  // o = attn @ v
#pragma unroll
  for (int t = 0; t < 8; ++t) {
    int idx = tid + t * 256;
    int i = idx >> 5, d = idx & 31;
    float acc = 0.f;
#pragma unroll
    for (int j = 0; j < 64; ++j) acc += s1[i][j] * vs[j][d];
    o[(size_t)(w * 64 + i) * DMODEL + head * 32 + d] = acc;
  }
}

// ---------------------------------------------------------------------------
extern "C" void kernel_launch(void* const* d_in, const int* in_sizes, int n_in,
                              void* d_out, int out_size, void* d_ws, size_t ws_size,
                              hipStream_t stream) {
  const float* x        = (const float*)d_in[0];
  const float* W_patch  = (const float*)d_in[1];
  const float* b_patch  = (const float*)d_in[2];
  const float* ln1_g    = (const float*)d_in[3];
  const float* ln1_b    = (const float*)d_in[4];
  const float* Wqkv     = (const float*)d_in[5];
  const float* headsita = (const float*)d_in[6];
  const float* bias_tbl = (const float*)d_in[7];
  const float* Wout     = (const float*)d_in[8];
  const float* bout     = (const float*)d_in[9];
  const float* ln2_g    = (const float*)d_in[10];
  const float* ln2_b    = (const float*)d_in[11];
  const float* W1       = (const float*)d_in[12];
  const float* b1       = (const float*)d_in[13];
  const float* W2       = (const float*)d_in[14];
  const float* b2       = (const float*)d_in[15];

  float* ws  = (float*)d_ws;
  float* t   = ws;                       // [65536,256]  64 MB (persistent)
  float* h   = ws + 16777216;            // [65536,256]  64 MB (LN out / gather)
  float* qkv = ws + 33554432;            // [65536,768] 192 MB
  float* o   = ws + 83886080;            // [65536,256]  64 MB
  float* hid = ws + 33554432;            // [65536,1024] 256 MB (overlaps qkv+o, both dead)

  float* out_img = (float*)d_out;              // [4,256,128,128]
  float* attns   = out_img + 16777216;         // [2,1024,8,64,64]

  // window partition + patch embedding
  gather_k<<<65536, 256, 0, stream>>>(x, h);
  gemm_k<true, false, false><<<dim3(DMODEL / 64, ROWS / 64), 256, 0, stream>>>(
      h, W_patch, b_patch, nullptr, t, ROWS, DMODEL, DMODEL);

  for (int l = 0; l < 2; ++l) {
    // LN1 -> h
    ln_k<<<ROWS, 256, 0, stream>>>(t, h, ln1_g + l * 256, ln1_b + l * 256);
    // qkv = h @ Wqkv[l]  (no bias)
    gemm_k<false, false, false><<<dim3(QKV_N / 64, ROWS / 64), 256, 0, stream>>>(
        h, Wqkv + (size_t)l * 256 * QKV_N, nullptr, nullptr, qkv, ROWS, QKV_N, DMODEL);
    // attention (also writes attns[l] to d_out)
    attn_k<<<dim3(NWIN, NHEADS), 256, 0, stream>>>(
        qkv, o, attns + (size_t)l * 33554432, bias_tbl + l * 225 * NHEADS,
        headsita + l * NHEADS);
    // t = o @ Wout[l] + bout[l] + t
    gemm_k<true, false, true><<<dim3(DMODEL / 64, ROWS / 64), 256, 0, stream>>>(
        o, Wout + (size_t)l * 256 * 256, bout + l * 256, t, t, ROWS, DMODEL, DMODEL);
    // LN2 -> h
    ln_k<<<ROWS, 256, 0, stream>>>(t, h, ln2_g + l * 256, ln2_b + l * 256);
    // hid = relu(h @ W1[l] + b1[l])
    gemm_k<true, true, false><<<dim3(MLP_N / 64, ROWS / 64), 256, 0, stream>>>(
        h, W1 + (size_t)l * 256 * MLP_N, b1 + l * MLP_N, nullptr, hid, ROWS, MLP_N, DMODEL);
    // t = hid @ W2[l] + b2[l] + t
    gemm_k<true, false, true><<<dim3(DMODEL / 64, ROWS / 64), 256, 0, stream>>>(
        hid, W2 + (size_t)l * MLP_N * 256, b2 + l * 256, t, t, ROWS, DMODEL, MLP_N);
  }

  // window reverse -> out image
  unwindow_k<<<65536, 256, 0, stream>>>(t, out_img);
}

// Round 2
// 1538.090 us; speedup vs baseline: 3.1198x; 3.1198x over previous
//
#include <hip/hip_runtime.h>
#include <hip/hip_bf16.h>
#include <cstddef>
#include <cstdint>

// ---------------------------------------------------------------------------
// StandardPartitionAttention — round 1: bf16 MFMA GEMMs (m97 recipe) +
// restructured attention. Residual stream fp32; activations bf16.
// ---------------------------------------------------------------------------

#define ROWS      65536
#define DMODEL    256
#define NWIN      1024
#define NHEADS    8
#define QKV_N     768
#define MLP_N     1024
#define SCALE_F   0.17677669529663687f
#define LN_EPS_F  1e-5f

typedef float f32x4 __attribute__((ext_vector_type(4)));
typedef __bf16 bf16x8 __attribute__((ext_vector_type(8)));

#define CP16(gp, lp)                                                          \
  __builtin_amdgcn_global_load_lds(                                           \
      (const __attribute__((address_space(1))) unsigned int*)(gp),            \
      (__attribute__((address_space(3))) unsigned int*)(lp), 16, 0, 0)

__device__ __forceinline__ float bf2f(ushort u) {
  return __uint_as_float(((unsigned)u) << 16);
}

// ---------------- window gather: x[B,C,H,W] -> Xg[row, c] (bf16) ------------
__global__ __launch_bounds__(256) void gather_k(const float* __restrict__ x,
                                                __hip_bfloat16* __restrict__ Xg) {
  size_t idx = (size_t)blockIdx.x * 256 + threadIdx.x;  // row*256 + c
  int c   = (int)(idx & 255);
  int row = (int)(idx >> 8);
  int i   = row & 63;
  int wxy = row >> 6;
  int wx  = wxy & 15;
  int wy  = (wxy >> 4) & 15;
  int b   = wxy >> 8;
  int y   = wy * 8 + (i >> 3);
  int xx  = wx * 8 + (i & 7);
  Xg[idx] = __float2bfloat16(x[(((size_t)b * 256 + c) * 128 + y) * 128 + xx]);
}

// ---------------- un-window: t[row, d] -> out[B,D,H,W] ----------------------
__global__ __launch_bounds__(256) void unwindow_k(const float* __restrict__ t,
                                                  float* __restrict__ out) {
  size_t idx = (size_t)blockIdx.x * 256 + threadIdx.x;
  int xx = (int)(idx & 127);
  size_t r = idx >> 7;
  int y = (int)(r & 127); r >>= 7;
  int d = (int)(r & 255);
  int b = (int)(r >> 8);
  int row = ((b * 16 + (y >> 3)) * 16 + (xx >> 3)) * 64 + (y & 7) * 8 + (xx & 7);
  out[idx] = t[(size_t)row * DMODEL + d];
}

// ---------------- weight transpose + bf16 convert: [K,N] f32 -> [N,K] bf16 --
__global__ __launch_bounds__(256) void transpose_k(const float* __restrict__ src,
                                                   __hip_bfloat16* __restrict__ dst,
                                                   int K, int N) {
  __shared__ float tile[32][33];
  int tx = threadIdx.x, ty = threadIdx.y;
  int n0 = blockIdx.x * 32, k0 = blockIdx.y * 32;
#pragma unroll
  for (int i = 0; i < 4; ++i)
    tile[ty + i * 8][tx] = src[(size_t)(k0 + ty + i * 8) * N + n0 + tx];
  __syncthreads();
#pragma unroll
  for (int i = 0; i < 4; ++i)
    dst[(size_t)(n0 + ty + i * 8) * K + k0 + tx] =
        __float2bfloat16(tile[tx][ty + i * 8]);
}

// ---------------- LayerNorm: fp32 in -> bf16 out ----------------------------
__global__ __launch_bounds__(256) void ln_k(const float* __restrict__ X,
                                            __hip_bfloat16* __restrict__ Y,
                                            const float* __restrict__ g,
                                            const float* __restrict__ b) {
  const int row = blockIdx.x;
  const int tid = threadIdx.x;
  float x = X[(size_t)row * DMODEL + tid];
  float s = x, s2 = x * x;
#pragma unroll
  for (int off = 32; off > 0; off >>= 1) {
    s  += __shfl_down(s,  off);
    s2 += __shfl_down(s2, off);
  }
  __shared__ float ls[4], ls2[4];
  int wave = tid >> 6, lane = tid & 63;
  if (lane == 0) { ls[wave] = s; ls2[wave] = s2; }
  __syncthreads();
  if (tid == 0) {
    float ts  = ls[0] + ls[1] + ls[2] + ls[3];
    float ts2 = ls2[0] + ls2[1] + ls2[2] + ls2[3];
    float m   = ts * (1.0f / DMODEL);
    float var = ts2 * (1.0f / DMODEL) - m * m;
    ls[0]  = m;
    ls2[0] = rsqrtf(var + LN_EPS_F);
  }
  __syncthreads();
  float m = ls[0], rr = ls2[0];
  Y[(size_t)row * DMODEL + tid] = __float2bfloat16((x - m) * rr * g[tid] + b[tid]);
}

// ---------------- bf16 MFMA GEMM: C = A[M,K] @ BT[N,K]^T (m97 structure) ----
// 128x128 tile, BK=32, 256 threads (4 waves, 2x2 of 64x64), 16 MFMA/K-step.
template <bool BIAS, bool RELU, bool RES, bool OBF16>
__global__ __launch_bounds__(256) void mm_k(const ushort* __restrict__ A,
                                            const ushort* __restrict__ BT,
                                            const float* __restrict__ bias,
                                            const float* __restrict__ res,
                                            void* __restrict__ Cout,
                                            int M, int N, int K) {
  __shared__ ushort As[4096];   // [128][32] bf16, unpadded (global_load_lds order)
  __shared__ ushort Bs[4096];   // [128][32] bf16 (rows of BT)
  const int tid = threadIdx.x;
  const int bm = blockIdx.y << 7, bn = blockIdx.x << 7;
  const ushort* Ap = A + (size_t)(bm + (tid >> 2)) * K + ((tid & 3) << 3);
  const ushort* Bp = BT + (size_t)(bn + (tid >> 2)) * K + ((tid & 3) << 3);
  const size_t k64 = (size_t)64 * K;
  const int lane = tid & 63, wave = tid >> 6;
  const int wm = (wave & 1) << 6, wn = (wave >> 1) << 6;
  const int lrow = lane & 15, kq = lane >> 4;
  const ushort* aF = &As[(wm + lrow) * 32 + kq * 8];
  const ushort* bF = &Bs[(wn + lrow) * 32 + kq * 8];
  f32x4 acc[4][4] = {};
  for (int k0 = 0; k0 < K; k0 += 32) {
    __syncthreads();              // previous iteration's ds_reads complete
    CP16(Ap, &As[tid * 8]);       // rows 0..63
    CP16(Ap + k64, &As[2048 + tid * 8]);
    CP16(Bp, &Bs[tid * 8]);
    CP16(Bp + k64, &Bs[2048 + tid * 8]);
    Ap += 32; Bp += 32;
    __syncthreads();              // waits vmcnt(0): LDS tiles filled
    bf16x8 af[4], bf[4];
#pragma unroll
    for (int i = 0; i < 4; ++i) af[i] = *(const bf16x8*)(aF + i * 512);
#pragma unroll
    for (int j = 0; j < 4; ++j) bf[j] = *(const bf16x8*)(bF + j * 512);
#pragma unroll
    for (int i = 0; i < 4; ++i)
#pragma unroll
      for (int j = 0; j < 4; ++j)
        acc[i][j] =
            __builtin_amdgcn_mfma_f32_16x16x32_bf16(af[i], bf[j], acc[i][j], 0, 0, 0);
  }
  // epilogue: C/D layout col = lane&15, row = kq*4 + reg
  const int r0 = bm + wm + kq * 4;
  const int c0 = bn + wn + lrow;
#pragma unroll
  for (int i = 0; i < 4; ++i) {
#pragma unroll
    for (int j = 0; j < 4; ++j) {
      const int col = c0 + j * 16;
      const float bv = BIAS ? bias[col] : 0.f;
#pragma unroll
      for (int r = 0; r < 4; ++r) {
        const int row = r0 + i * 16 + r;
        float v = acc[i][j][r] + bv;
        if (RELU) v = fmaxf(v, 0.f);
        if (RES) v += res[(size_t)row * N + col];
        if (OBF16)
          ((__hip_bfloat16*)Cout)[(size_t)row * N + col] = __float2bfloat16(v);
        else
          ((float*)Cout)[(size_t)row * N + col] = v;
      }
    }
  }
}

// ---------------- attention v2: block per (window, head), 256 threads -------
__global__ __launch_bounds__(256) void attn_k(const ushort* __restrict__ qkv,
                                              __hip_bfloat16* __restrict__ o,
                                              float* __restrict__ attns_out,
                                              const float* __restrict__ bias_tbl,
                                              const float* __restrict__ sita_l) {
  const int w = blockIdx.x, head = blockIdx.y, tid = threadIdx.x;
  __shared__ float qs[64][36], ks[64][36], vs[64][36];
  __shared__ float s1[64][68];
  __shared__ float btbl[225];

  if (tid < 225) btbl[tid] = bias_tbl[tid * NHEADS + head];

  // stage q,k,v (bf16 -> f32), one uint4 (8 bf16) per thread per matrix
  {
    const int i = tid >> 2, c = (tid & 3) * 8;
    const size_t rb = (size_t)(w * 64 + i) * QKV_N + head * 32 + c;
    union { uint4 u; ushort s[8]; } U;
    U.u = *(const uint4*)(qkv + rb);
#pragma unroll
    for (int z = 0; z < 8; ++z) qs[i][c + z] = bf2f(U.s[z]);
    U.u = *(const uint4*)(qkv + rb + 256);
#pragma unroll
    for (int z = 0; z < 8; ++z) ks[i][c + z] = bf2f(U.s[z]);
    U.u = *(const uint4*)(qkv + rb + 512);
#pragma unroll
    for (int z = 0; z < 8; ++z) vs[i][c + z] = bf2f(U.s[z]);
  }
  __syncthreads();

  const int i = tid >> 2, jq = tid & 3;
  const float sita = sita_l[head];
  const float factor = 1.0f / (2.0f * sita * sita + 1e-10f);
  const int iy = i >> 3, ix = i & 7;

  // q row into registers
  float ql[32];
#pragma unroll
  for (int c = 0; c < 8; ++c) *(float4*)&ql[c * 4] = *(const float4*)&qs[i][c * 4];

  // 16 scores per thread (columns jq*16 .. +15)
  float d0[16], e1[16];
#pragma unroll
  for (int jj = 0; jj < 16; ++jj) {
    const int j = jq * 16 + jj;
    float dot = 0.f;
#pragma unroll
    for (int cc = 0; cc < 8; ++cc) {
      const int c = (cc + jq * 2) & 7;   // rotate start chunk: kills 4-way conflict
      const float4 kv = *(const float4*)&ks[j][c * 4];
      dot += ql[c * 4] * kv.x + ql[c * 4 + 1] * kv.y +
             ql[c * 4 + 2] * kv.z + ql[c * 4 + 3] * kv.w;
    }
    const float v0 = dot * SCALE_F;
    const int jy = j >> 3, jx = j & 7;
    const float dy = (float)(iy - jy) * 0.125f;
    const float dx = (float)(ix - jx) * 0.125f;
    const float bias = btbl[(iy - jy + 7) * 15 + (ix - jx + 7)];
    d0[jj] = v0;
    e1[jj] = v0 + bias + 0.01f * __expf(-factor * (dy * dy + dx * dx));
  }

  // softmax over the row, split across the 4 lanes jq (same wave)
  float m0 = -1e30f, m1 = -1e30f;
#pragma unroll
  for (int jj = 0; jj < 16; ++jj) {
    m0 = fmaxf(m0, d0[jj]);
    m1 = fmaxf(m1, e1[jj]);
  }
  m0 = fmaxf(m0, __shfl_xor(m0, 1)); m0 = fmaxf(m0, __shfl_xor(m0, 2));
  m1 = fmaxf(m1, __shfl_xor(m1, 1)); m1 = fmaxf(m1, __shfl_xor(m1, 2));
  float z0 = 0.f, z1 = 0.f;
#pragma unroll
  for (int jj = 0; jj < 16; ++jj) {
    d0[jj] = __expf(d0[jj] - m0); z0 += d0[jj];
    e1[jj] = __expf(e1[jj] - m1); z1 += e1[jj];
  }
  z0 += __shfl_xor(z0, 1); z0 += __shfl_xor(z0, 2);
  z1 += __shfl_xor(z1, 1); z1 += __shfl_xor(z1, 2);
  const float r0 = 1.f / z0, r1 = 1.f / z1;

  // write attns (softmax of dots0) straight to d_out, float4-vectorized
  const size_t ab = (((size_t)(w * NHEADS + head)) * 64 + i) * 64 + jq * 16;
#pragma unroll
  for (int c4 = 0; c4 < 4; ++c4) {
    float4 t4 = make_float4(d0[c4 * 4] * r0, d0[c4 * 4 + 1] * r0,
                            d0[c4 * 4 + 2] * r0, d0[c4 * 4 + 3] * r0);
    *(float4*)(attns_out + ab + c4 * 4) = t4;
  }
#pragma unroll
  for (int jj = 0; jj < 16; ++jj) s1[i][jq * 16 + jj] = e1[jj] * r1;
  __syncthreads();

  // AV: thread (i, dq): 8 output dims
  const int dq = tid & 3;
  float acc[8] = {};
#pragma unroll
  for (int j = 0; j < 64; ++j) {
    const float a = s1[i][j];
    const float4 v0 = *(const float4*)&vs[j][dq * 8];
    const float4 v1 = *(const float4*)&vs[j][dq * 8 + 4];
    acc[0] += a * v0.x; acc[1] += a * v0.y; acc[2] += a * v0.z; acc[3] += a * v0.w;
    acc[4] += a * v1.x; acc[5] += a * v1.y; acc[6] += a * v1.z; acc[7] += a * v1.w;
  }
  union { uint4 u; __hip_bfloat16 b[8]; } O;
#pragma unroll
  for (int z = 0; z < 8; ++z) O.b[z] = __float2bfloat16(acc[z]);
  *(uint4*)((ushort*)o + (size_t)(w * 64 + i) * DMODEL + head * 32 + dq * 8) = O.u;
}

// ---------------------------------------------------------------------------
extern "C" void kernel_launch(void* const* d_in, const int* in_sizes, int n_in,
                              void* d_out, int out_size, void* d_ws, size_t ws_size,
                              hipStream_t stream) {
  const float* x        = (const float*)d_in[0];
  const float* W_patch  = (const float*)d_in[1];
  const float* b_patch  = (const float*)d_in[2];
  const float* ln1_g    = (const float*)d_in[3];
  const float* ln1_b    = (const float*)d_in[4];
  const float* Wqkv     = (const float*)d_in[5];
  const float* headsita = (const float*)d_in[6];
  const float* bias_tbl = (const float*)d_in[7];
  const float* Wout     = (const float*)d_in[8];
  const float* bout     = (const float*)d_in[9];
  const float* ln2_g    = (const float*)d_in[10];
  const float* ln2_b    = (const float*)d_in[11];
  const float* W1       = (const float*)d_in[12];
  const float* b1       = (const float*)d_in[13];
  const float* W2       = (const float*)d_in[14];
  const float* b2       = (const float*)d_in[15];

  char* W = (char*)d_ws;
  float*  t   = (float*)W;                       // [65536,256] f32, 64 MB
  ushort* h   = (ushort*)(W + 67108864);         // [65536,256] bf16, 32 MB
  ushort* qkv = (ushort*)(W + 100663296);        // [65536,768] bf16, 96 MB
  ushort* o   = (ushort*)(W + 201326592);        // [65536,256] bf16, 32 MB
  ushort* wT  = (ushort*)(W + 234881024);        // transposed bf16 weights
  ushort* Xg  = qkv;                             // overlap (dead before qkv GEMM)
  ushort* hid = qkv;                             // [65536,1024] bf16 (qkv+o dead)

  ushort* WpT   = wT;                 // [256,256]
  ushort* WqkvT = wT + 65536;         // 2 x [768,256]
  ushort* WoutT = wT + 458752;        // 2 x [256,256]
  ushort* W1T   = wT + 589824;        // 2 x [1024,256]
  ushort* W2T   = wT + 1114112;       // 2 x [256,1024]

  float* out_img = (float*)d_out;
  float* attns   = out_img + 16777216;

  const dim3 tb(32, 8);
  transpose_k<<<dim3(8, 8),  tb, 0, stream>>>(W_patch, (__hip_bfloat16*)WpT, 256, 256);
  for (int l = 0; l < 2; ++l) {
    transpose_k<<<dim3(24, 8), tb, 0, stream>>>(Wqkv + (size_t)l * 196608,
        (__hip_bfloat16*)(WqkvT + (size_t)l * 196608), 256, 768);
    transpose_k<<<dim3(8, 8),  tb, 0, stream>>>(Wout + (size_t)l * 65536,
        (__hip_bfloat16*)(WoutT + (size_t)l * 65536), 256, 256);
    transpose_k<<<dim3(32, 8), tb, 0, stream>>>(W1 + (size_t)l * 262144,
        (__hip_bfloat16*)(W1T + (size_t)l * 262144), 256, 1024);
    transpose_k<<<dim3(8, 32), tb, 0, stream>>>(W2 + (size_t)l * 262144,
        (__hip_bfloat16*)(W2T + (size_t)l * 262144), 1024, 256);
  }

  gather_k<<<65536, 256, 0, stream>>>(x, (__hip_bfloat16*)Xg);
  mm_k<true, false, false, false><<<dim3(2, 512), 256, 0, stream>>>(
      Xg, WpT, b_patch, nullptr, t, ROWS, DMODEL, DMODEL);

  for (int l = 0; l < 2; ++l) {
    ln_k<<<ROWS, 256, 0, stream>>>(t, (__hip_bfloat16*)h, ln1_g + l * 256, ln1_b + l * 256);
    mm_k<false, false, false, true><<<dim3(6, 512), 256, 0, stream>>>(
        h, WqkvT + (size_t)l * 196608, nullptr, nullptr, qkv, ROWS, QKV_N, DMODEL);
    attn_k<<<dim3(NWIN, NHEADS), 256, 0, stream>>>(
        qkv, (__hip_bfloat16*)o, attns + (size_t)l * 33554432,
        bias_tbl + l * 225 * NHEADS, headsita + l * NHEADS);
    mm_k<true, false, true, false><<<dim3(2, 512), 256, 0, stream>>>(
        o, WoutT + (size_t)l * 65536, bout + l * 256, t, t, ROWS, DMODEL, DMODEL);
    ln_k<<<ROWS, 256, 0, stream>>>(t, (__hip_bfloat16*)h, ln2_g + l * 256, ln2_b + l * 256);
    mm_k<true, true, false, true><<<dim3(8, 512), 256, 0, stream>>>(
        h, W1T + (size_t)l * 262144, b1 + l * MLP_N, nullptr, hid, ROWS, MLP_N, DMODEL);
    mm_k<true, false, true, false><<<dim3(2, 512), 256, 0, stream>>>(
        hid, W2T + (size_t)l * 262144, b2 + l * 256, t, t, ROWS, DMODEL, MLP_N);
  }

  unwindow_k<<<65536, 256, 0, stream>>>(t, out_img);
}

// Round 3
// 1371.578 us; speedup vs baseline: 3.4986x; 1.1214x over previous
//
#include <hip/hip_runtime.h>
#include <hip/hip_bf16.h>
#include <cstddef>
#include <cstdint>

// ---------------------------------------------------------------------------
// StandardPartitionAttention — round 2: MFMA attention (wave per (w,h)) +
// LN fused into N=256 GEMM epilogues. bf16 activations, fp32 residual.
// ---------------------------------------------------------------------------

#define ROWS      65536
#define DMODEL    256
#define NWIN      1024
#define NHEADS    8
#define QKV_N     768
#define MLP_N     1024
#define SCALE_F   0.17677669529663687f
#define LN_EPS_F  1e-5f

typedef float f32x4 __attribute__((ext_vector_type(4)));
typedef __bf16 bf16x8 __attribute__((ext_vector_type(8)));

#define CP16(gp, lp)                                                          \
  __builtin_amdgcn_global_load_lds(                                           \
      (const __attribute__((address_space(1))) unsigned int*)(gp),            \
      (__attribute__((address_space(3))) unsigned int*)(lp), 16, 0, 0)

// ---------------- window gather: x[B,C,H,W] -> Xg[row, c] (bf16) ------------
__global__ __launch_bounds__(256) void gather_k(const float* __restrict__ x,
                                                __hip_bfloat16* __restrict__ Xg) {
  size_t idx = (size_t)blockIdx.x * 256 + threadIdx.x;
  int c   = (int)(idx & 255);
  int row = (int)(idx >> 8);
  int i   = row & 63;
  int wxy = row >> 6;
  int wx  = wxy & 15;
  int wy  = (wxy >> 4) & 15;
  int b   = wxy >> 8;
  int y   = wy * 8 + (i >> 3);
  int xx  = wx * 8 + (i & 7);
  Xg[idx] = __float2bfloat16(x[(((size_t)b * 256 + c) * 128 + y) * 128 + xx]);
}

// ---------------- un-window: t[row, d] -> out[B,D,H,W] ----------------------
__global__ __launch_bounds__(256) void unwindow_k(const float* __restrict__ t,
                                                  float* __restrict__ out) {
  size_t idx = (size_t)blockIdx.x * 256 + threadIdx.x;
  int xx = (int)(idx & 127);
  size_t r = idx >> 7;
  int y = (int)(r & 127); r >>= 7;
  int d = (int)(r & 255);
  int b = (int)(r >> 8);
  int row = ((b * 16 + (y >> 3)) * 16 + (xx >> 3)) * 64 + (y & 7) * 8 + (xx & 7);
  out[idx] = t[(size_t)row * DMODEL + d];
}

// ---------------- weight transpose + bf16 convert: [K,N] f32 -> [N,K] bf16 --
__global__ __launch_bounds__(256) void transpose_k(const float* __restrict__ src,
                                                   __hip_bfloat16* __restrict__ dst,
                                                   int K, int N) {
  __shared__ float tile[32][33];
  int tx = threadIdx.x, ty = threadIdx.y;
  int n0 = blockIdx.x * 32, k0 = blockIdx.y * 32;
#pragma unroll
  for (int i = 0; i < 4; ++i)
    tile[ty + i * 8][tx] = src[(size_t)(k0 + ty + i * 8) * N + n0 + tx];
  __syncthreads();
#pragma unroll
  for (int i = 0; i < 4; ++i)
    dst[(size_t)(n0 + ty + i * 8) * K + k0 + tx] =
        __float2bfloat16(tile[tx][ty + i * 8]);
}

// ---------------- bf16 MFMA GEMM (m97 structure, proven round 1) ------------
template <bool BIAS, bool RELU, bool RES, bool OBF16>
__global__ __launch_bounds__(256) void mm_k(const ushort* __restrict__ A,
                                            const ushort* __restrict__ BT,
                                            const float* __restrict__ bias,
                                            const float* __restrict__ res,
                                            void* __restrict__ Cout,
                                            int M, int N, int K) {
  __shared__ ushort As[4096];
  __shared__ ushort Bs[4096];
  const int tid = threadIdx.x;
  const int bm = blockIdx.y << 7, bn = blockIdx.x << 7;
  const ushort* Ap = A + (size_t)(bm + (tid >> 2)) * K + ((tid & 3) << 3);
  const ushort* Bp = BT + (size_t)(bn + (tid >> 2)) * K + ((tid & 3) << 3);
  const size_t k64 = (size_t)64 * K;
  const int lane = tid & 63, wave = tid >> 6;
  const int wm = (wave & 1) << 6, wn = (wave >> 1) << 6;
  const int lrow = lane & 15, kq = lane >> 4;
  const ushort* aF = &As[(wm + lrow) * 32 + kq * 8];
  const ushort* bF = &Bs[(wn + lrow) * 32 + kq * 8];
  f32x4 acc[4][4] = {};
  for (int k0 = 0; k0 < K; k0 += 32) {
    __syncthreads();
    CP16(Ap, &As[tid * 8]);
    CP16(Ap + k64, &As[2048 + tid * 8]);
    CP16(Bp, &Bs[tid * 8]);
    CP16(Bp + k64, &Bs[2048 + tid * 8]);
    Ap += 32; Bp += 32;
    __syncthreads();
    bf16x8 af[4], bf[4];
#pragma unroll
    for (int i = 0; i < 4; ++i) af[i] = *(const bf16x8*)(aF + i * 512);
#pragma unroll
    for (int j = 0; j < 4; ++j) bf[j] = *(const bf16x8*)(bF + j * 512);
#pragma unroll
    for (int i = 0; i < 4; ++i)
#pragma unroll
      for (int j = 0; j < 4; ++j)
        acc[i][j] =
            __builtin_amdgcn_mfma_f32_16x16x32_bf16(af[i], bf[j], acc[i][j], 0, 0, 0);
  }
  const int r0 = bm + wm + kq * 4;
  const int c0 = bn + wn + lrow;
#pragma unroll
  for (int i = 0; i < 4; ++i) {
#pragma unroll
    for (int j = 0; j < 4; ++j) {
      const int col = c0 + j * 16;
      const float bv = BIAS ? bias[col] : 0.f;
#pragma unroll
      for (int r = 0; r < 4; ++r) {
        const int row = r0 + i * 16 + r;
        float v = acc[i][j][r] + bv;
        if (RELU) v = fmaxf(v, 0.f);
        if (RES) v += res[(size_t)row * N + col];
        if (OBF16)
          ((__hip_bfloat16*)Cout)[(size_t)row * N + col] = __float2bfloat16(v);
        else
          ((float*)Cout)[(size_t)row * N + col] = v;
      }
    }
  }
}

// ---------------- GEMM (N=256, tile 64x256) + fused LayerNorm ---------------
// Writes Tout (f32 residual stream) and Hout (bf16 LN output).
template <bool RES>
__global__ __launch_bounds__(256) void mm_ln_k(const ushort* __restrict__ A,
                                               const ushort* __restrict__ BT,
                                               const float* __restrict__ bias,
                                               const float* __restrict__ res,
                                               float* __restrict__ Tout,
                                               __hip_bfloat16* __restrict__ Hout,
                                               const float* __restrict__ g,
                                               const float* __restrict__ bb,
                                               int K) {
  __shared__ ushort As[2048];      // 64 x 32
  __shared__ ushort Bs[8192];      // 256 x 32
  __shared__ float rs[64][4], rs2[64][4];
  const int tid = threadIdx.x;
  const int bm = blockIdx.x << 6;
  const ushort* Ap = A + (size_t)(bm + (tid >> 2)) * K + ((tid & 3) << 3);
  const ushort* Bp = BT + (size_t)(tid >> 2) * K + ((tid & 3) << 3);
  const size_t k64 = (size_t)64 * K;
  const int lane = tid & 63, wave = tid >> 6;
  const int l15 = lane & 15, quad = lane >> 4;
  const ushort* aF = &As[l15 * 32 + quad * 8];
  const ushort* bF = &Bs[(wave * 64 + l15) * 32 + quad * 8];
  f32x4 acc[4][4] = {};
  for (int k0 = 0; k0 < K; k0 += 32) {
    __syncthreads();
    CP16(Ap, &As[tid * 8]);
    CP16(Bp, &Bs[tid * 8]);
    CP16(Bp + k64, &Bs[2048 + tid * 8]);
    CP16(Bp + 2 * k64, &Bs[4096 + tid * 8]);
    CP16(Bp + 3 * k64, &Bs[6144 + tid * 8]);
    Ap += 32; Bp += 32;
    __syncthreads();
    bf16x8 af[4], bf[4];
#pragma unroll
    for (int i = 0; i < 4; ++i) af[i] = *(const bf16x8*)(aF + i * 512);
#pragma unroll
    for (int j = 0; j < 4; ++j) bf[j] = *(const bf16x8*)(bF + j * 512);
#pragma unroll
    for (int i = 0; i < 4; ++i)
#pragma unroll
      for (int j = 0; j < 4; ++j)
        acc[i][j] =
            __builtin_amdgcn_mfma_f32_16x16x32_bf16(af[i], bf[j], acc[i][j], 0, 0, 0);
  }
  // epilogue: bias (+res), then full-row LN across 256 cols
  const int rb = quad * 4;
#pragma unroll
  for (int i = 0; i < 4; ++i)
#pragma unroll
    for (int j = 0; j < 4; ++j) {
      const int col = wave * 64 + j * 16 + l15;
      const float bv = bias[col];
#pragma unroll
      for (int r = 0; r < 4; ++r) {
        const int row = bm + i * 16 + rb + r;
        float x = acc[i][j][r] + bv;
        if (RES) x += res[(size_t)row * 256 + col];
        acc[i][j][r] = x;
      }
    }
#pragma unroll
  for (int i = 0; i < 4; ++i)
#pragma unroll
    for (int r = 0; r < 4; ++r) {
      float s = 0.f, s2 = 0.f;
#pragma unroll
      for (int j = 0; j < 4; ++j) {
        float x = acc[i][j][r];
        s += x; s2 += x * x;
      }
      s += __shfl_xor(s, 1);  s += __shfl_xor(s, 2);
      s += __shfl_xor(s, 4);  s += __shfl_xor(s, 8);
      s2 += __shfl_xor(s2, 1); s2 += __shfl_xor(s2, 2);
      s2 += __shfl_xor(s2, 4); s2 += __shfl_xor(s2, 8);
      if (l15 == 0) {
        rs[i * 16 + rb + r][wave] = s;
        rs2[i * 16 + rb + r][wave] = s2;
      }
    }
  __syncthreads();
  float mrow[4][4], rrow[4][4];
#pragma unroll
  for (int i = 0; i < 4; ++i)
#pragma unroll
    for (int r = 0; r < 4; ++r) {
      const int lr = i * 16 + rb + r;
      float4 s4 = *(const float4*)rs[lr];
      float4 q4 = *(const float4*)rs2[lr];
      float tot = s4.x + s4.y + s4.z + s4.w;
      float tot2 = q4.x + q4.y + q4.z + q4.w;
      float m = tot * (1.0f / 256.0f);
      float var = tot2 * (1.0f / 256.0f) - m * m;
      mrow[i][r] = m;
      rrow[i][r] = rsqrtf(var + LN_EPS_F);
    }
#pragma unroll
  for (int i = 0; i < 4; ++i)
#pragma unroll
    for (int j = 0; j < 4; ++j) {
      const int col = wave * 64 + j * 16 + l15;
      const float gv = g[col], bv = bb[col];
#pragma unroll
      for (int r = 0; r < 4; ++r) {
        const int row = bm + i * 16 + rb + r;
        float x = acc[i][j][r];
        Tout[(size_t)row * 256 + col] = x;
        Hout[(size_t)row * 256 + col] =
            __float2bfloat16((x - mrow[i][r]) * rrow[i][r] * gv + bv);
      }
    }
}

// ---------------- attention v3: MFMA, one wave per (window, head) -----------
// Block = 4 waves = 4 windows, one head (shared bias+pos table). No barriers
// after staging. q/k row-major (A / B^T layouts for QK^T); V staged transposed.
__global__ __launch_bounds__(256) void attn_k(const ushort* __restrict__ qkv,
                                              __hip_bfloat16* __restrict__ o,
                                              float* __restrict__ attns_out,
                                              const float* __restrict__ bias_tbl,
                                              const float* __restrict__ sita_l) {
  // per-wave region: q 64x40 (2560), k 64x40 (2560), vT 32x72 (2304) = 7424 ush
  __shared__ ushort smem[4 * 7424];
  __shared__ float tbl[225];
  const int tid = threadIdx.x;
  const int lane = tid & 63, wave = tid >> 6;
  const int head = blockIdx.x & 7;
  const int w = ((blockIdx.x >> 3) << 2) + wave;
  ushort* qw = smem + wave * 7424;
  ushort* kw = qw + 2560;
  ushort* vw = kw + 2560;
  ushort* Pw = qw;                 // 64x72 = 4608 <= 5120 (q+k dead after QK)

  const float sita = sita_l[head];
  const float factor = 1.0f / (2.0f * sita * sita + 1e-10f);
  for (int idx = tid; idx < 225; idx += 256) {
    int dyi = idx / 15 - 7, dxi = idx % 15 - 7;
    float dis = (float)(dyi * dyi + dxi * dxi) * 0.015625f;
    tbl[idx] = bias_tbl[idx * NHEADS + head] + 0.01f * __expf(-factor * dis);
  }

  // stage q,k row-major [tok][d]; v transposed [d][tok]
  {
    const ushort* base = qkv + (size_t)(w * 64) * QKV_N + head * 32;
    const int r0 = lane >> 2, c = (lane & 3) << 3;
#pragma unroll
    for (int r4 = 0; r4 < 4; ++r4) {
      const int row = r4 * 16 + r0;
      const ushort* rp = base + (size_t)row * QKV_N + c;
      *(uint4*)(qw + row * 40 + c) = *(const uint4*)(rp);
      *(uint4*)(kw + row * 40 + c) = *(const uint4*)(rp + 256);
      union { uint4 u; ushort s[8]; } V;
      V.u = *(const uint4*)(rp + 512);
#pragma unroll
      for (int z = 0; z < 8; ++z) vw[(c + z) * 72 + row] = V.s[z];
    }
  }
  __syncthreads();

  const int l15 = lane & 15, quad = lane >> 4;

  // QK^T: 16 MFMA, C-layout acc
  f32x4 acc[4][4] = {};
  {
    bf16x8 af[4], bfr[4];
#pragma unroll
    for (int i = 0; i < 4; ++i)
      af[i] = *(const bf16x8*)(qw + (i * 16 + l15) * 40 + quad * 8);
#pragma unroll
    for (int j = 0; j < 4; ++j)
      bfr[j] = *(const bf16x8*)(kw + (j * 16 + l15) * 40 + quad * 8);
#pragma unroll
    for (int i = 0; i < 4; ++i)
#pragma unroll
      for (int j = 0; j < 4; ++j)
        acc[i][j] =
            __builtin_amdgcn_mfma_f32_16x16x32_bf16(af[i], bfr[j], acc[i][j], 0, 0, 0);
  }

  // scores: acc <- dots0 (scaled); e1 <- dots0 + bias + 0.01*pos
  float e1[4][4][4];
#pragma unroll
  for (int i = 0; i < 4; ++i)
#pragma unroll
    for (int r = 0; r < 4; ++r) {
      const int row = i * 16 + quad * 4 + r;
      const int iy = row >> 3, ix = row & 7;
#pragma unroll
      for (int j = 0; j < 4; ++j) {
        const int col = j * 16 + l15;
        const int jy = col >> 3, jx = col & 7;
        float d0 = acc[i][j][r] * SCALE_F;
        acc[i][j][r] = d0;
        e1[i][j][r] = d0 + tbl[(iy - jy + 7) * 15 + (ix - jx + 7)];
      }
    }

  // dual softmax per row (lane-group of 16 holds a row across 4 j-tiles)
#pragma unroll
  for (int i = 0; i < 4; ++i)
#pragma unroll
    for (int r = 0; r < 4; ++r) {
      float m0 = -1e30f, m1 = -1e30f;
#pragma unroll
      for (int j = 0; j < 4; ++j) {
        m0 = fmaxf(m0, acc[i][j][r]);
        m1 = fmaxf(m1, e1[i][j][r]);
      }
      m0 = fmaxf(m0, __shfl_xor(m0, 1)); m0 = fmaxf(m0, __shfl_xor(m0, 2));
      m0 = fmaxf(m0, __shfl_xor(m0, 4)); m0 = fmaxf(m0, __shfl_xor(m0, 8));
      m1 = fmaxf(m1, __shfl_xor(m1, 1)); m1 = fmaxf(m1, __shfl_xor(m1, 2));
      m1 = fmaxf(m1, __shfl_xor(m1, 4)); m1 = fmaxf(m1, __shfl_xor(m1, 8));
      float z0 = 0.f, z1 = 0.f;
#pragma unroll
      for (int j = 0; j < 4; ++j) {
        float a = __expf(acc[i][j][r] - m0); acc[i][j][r] = a; z0 += a;
        float bqq = __expf(e1[i][j][r] - m1); e1[i][j][r] = bqq; z1 += bqq;
      }
      z0 += __shfl_xor(z0, 1); z0 += __shfl_xor(z0, 2);
      z0 += __shfl_xor(z0, 4); z0 += __shfl_xor(z0, 8);
      z1 += __shfl_xor(z1, 1); z1 += __shfl_xor(z1, 2);
      z1 += __shfl_xor(z1, 4); z1 += __shfl_xor(z1, 8);
      const float r0i = 1.f / z0, r1i = 1.f / z1;
#pragma unroll
      for (int j = 0; j < 4; ++j) {
        acc[i][j][r] *= r0i;
        e1[i][j][r] *= r1i;
      }
    }

  // write attns (softmax of dots0) to d_out
  {
    float* ab = attns_out + ((size_t)(w * NHEADS + head)) * 4096;
#pragma unroll
    for (int i = 0; i < 4; ++i)
#pragma unroll
      for (int j = 0; j < 4; ++j)
#pragma unroll
        for (int r = 0; r < 4; ++r)
          ab[(i * 16 + quad * 4 + r) * 64 + j * 16 + l15] = acc[i][j][r];
  }

  // P (biased softmax) -> LDS row-major bf16 (A-operand layout for AV)
#pragma unroll
  for (int i = 0; i < 4; ++i)
#pragma unroll
    for (int j = 0; j < 4; ++j)
#pragma unroll
      for (int r = 0; r < 4; ++r)
        Pw[(i * 16 + quad * 4 + r) * 72 + j * 16 + l15] =
            ((__hip_bfloat16_raw)__float2bfloat16(e1[i][j][r])).x;

  // AV: O = P @ V  (M=64, N=32, K=64 -> 16 MFMA)
  f32x4 oacc[4][2] = {};
#pragma unroll
  for (int ks = 0; ks < 2; ++ks) {
    bf16x8 pa[4], vb[2];
#pragma unroll
    for (int i = 0; i < 4; ++i)
      pa[i] = *(const bf16x8*)(Pw + (i * 16 + l15) * 72 + ks * 32 + quad * 8);
#pragma unroll
    for (int j = 0; j < 2; ++j)
      vb[j] = *(const bf16x8*)(vw + (j * 16 + l15) * 72 + ks * 32 + quad * 8);
#pragma unroll
    for (int i = 0; i < 4; ++i)
#pragma unroll
      for (int j = 0; j < 2; ++j)
        oacc[i][j] =
            __builtin_amdgcn_mfma_f32_16x16x32_bf16(pa[i], vb[j], oacc[i][j], 0, 0, 0);
  }
  {
    ushort* ob = (ushort*)o + (size_t)(w * 64) * DMODEL + head * 32;
#pragma unroll
    for (int i = 0; i < 4; ++i)
#pragma unroll
      for (int j = 0; j < 2; ++j)
#pragma unroll
        for (int r = 0; r < 4; ++r)
          ob[(size_t)(i * 16 + quad * 4 + r) * DMODEL + j * 16 + l15] =
              ((__hip_bfloat16_raw)__float2bfloat16(oacc[i][j][r])).x;
  }
}

// ---------------------------------------------------------------------------
extern "C" void kernel_launch(void* const* d_in, const int* in_sizes, int n_in,
                              void* d_out, int out_size, void* d_ws, size_t ws_size,
                              hipStream_t stream) {
  const float* x        = (const float*)d_in[0];
  const float* W_patch  = (const float*)d_in[1];
  const float* b_patch  = (const float*)d_in[2];
  const float* ln1_g    = (const float*)d_in[3];
  const float* ln1_b    = (const float*)d_in[4];
  const float* Wqkv     = (const float*)d_in[5];
  const float* headsita = (const float*)d_in[6];
  const float* bias_tbl = (const float*)d_in[7];
  const float* Wout     = (const float*)d_in[8];
  const float* bout     = (const float*)d_in[9];
  const float* ln2_g    = (const float*)d_in[10];
  const float* ln2_b    = (const float*)d_in[11];
  const float* W1       = (const float*)d_in[12];
  const float* b1       = (const float*)d_in[13];
  const float* W2       = (const float*)d_in[14];
  const float* b2       = (const float*)d_in[15];

  char* W = (char*)d_ws;
  float*  t   = (float*)W;                       // [65536,256] f32, 64 MB
  ushort* h   = (ushort*)(W + 67108864);         // [65536,256] bf16, 32 MB
  ushort* qkv = (ushort*)(W + 100663296);        // [65536,768] bf16, 96 MB
  ushort* o   = (ushort*)(W + 201326592);        // [65536,256] bf16, 32 MB
  ushort* wT  = (ushort*)(W + 234881024);        // transposed bf16 weights
  ushort* Xg  = qkv;                             // overlap (dead before qkv GEMM)
  ushort* hid = qkv;                             // [65536,1024] bf16

  ushort* WpT   = wT;
  ushort* WqkvT = wT + 65536;
  ushort* WoutT = wT + 458752;
  ushort* W1T   = wT + 589824;
  ushort* W2T   = wT + 1114112;

  float* out_img = (float*)d_out;
  float* attns   = out_img + 16777216;

  const dim3 tb(32, 8);
  transpose_k<<<dim3(8, 8),  tb, 0, stream>>>(W_patch, (__hip_bfloat16*)WpT, 256, 256);
  for (int l = 0; l < 2; ++l) {
    transpose_k<<<dim3(24, 8), tb, 0, stream>>>(Wqkv + (size_t)l * 196608,
        (__hip_bfloat16*)(WqkvT + (size_t)l * 196608), 256, 768);
    transpose_k<<<dim3(8, 8),  tb, 0, stream>>>(Wout + (size_t)l * 65536,
        (__hip_bfloat16*)(WoutT + (size_t)l * 65536), 256, 256);
    transpose_k<<<dim3(32, 8), tb, 0, stream>>>(W1 + (size_t)l * 262144,
        (__hip_bfloat16*)(W1T + (size_t)l * 262144), 256, 1024);
    transpose_k<<<dim3(8, 32), tb, 0, stream>>>(W2 + (size_t)l * 262144,
        (__hip_bfloat16*)(W2T + (size_t)l * 262144), 1024, 256);
  }

  gather_k<<<65536, 256, 0, stream>>>(x, (__hip_bfloat16*)Xg);
  // patch embed + fused LN1 (layer 0)
  mm_ln_k<false><<<1024, 256, 0, stream>>>(
      Xg, WpT, b_patch, nullptr, t, (__hip_bfloat16*)h, ln1_g, ln1_b, 256);

  for (int l = 0; l < 2; ++l) {
    mm_k<false, false, false, true><<<dim3(6, 512), 256, 0, stream>>>(
        h, WqkvT + (size_t)l * 196608, nullptr, nullptr, qkv, ROWS, QKV_N, DMODEL);
    attn_k<<<2048, 256, 0, stream>>>(
        qkv, (__hip_bfloat16*)o, attns + (size_t)l * 33554432,
        bias_tbl + l * 225 * NHEADS, headsita + l * NHEADS);
    // out-proj + residual + fused LN2
    mm_ln_k<true><<<1024, 256, 0, stream>>>(
        o, WoutT + (size_t)l * 65536, bout + l * 256, t, t, (__hip_bfloat16*)h,
        ln2_g + l * 256, ln2_b + l * 256, 256);
    mm_k<true, true, false, true><<<dim3(8, 512), 256, 0, stream>>>(
        h, W1T + (size_t)l * 262144, b1 + l * MLP_N, nullptr, hid, ROWS, MLP_N, DMODEL);
    if (l == 0) {
      // W2 + residual + fused LN1 of layer 1
      mm_ln_k<true><<<1024, 256, 0, stream>>>(
          hid, W2T, b2, t, t, (__hip_bfloat16*)h, ln1_g + 256, ln1_b + 256, 1024);
    } else {
      mm_k<true, false, true, false><<<dim3(2, 512), 256, 0, stream>>>(
          hid, W2T + 262144, b2 + 256, t, t, ROWS, DMODEL, MLP_N);
    }
  }

  unwindow_k<<<65536, 256, 0, stream>>>(t, out_img);
}